// Round 1
// baseline (5327.684 us; speedup 1.0000x reference)
//
#include <hip/hip_runtime.h>
#include <hip/hip_bf16.h>
#include <stdint.h>

// Sizes (fixed by the problem)
#define BB 512      // batch
#define TT 128      // seq len
#define DD 1024     // input dim / hidden
#define HH 1024
#define G3 3072     // 3*H
#define TC 32       // time chunk
#define NCH (TT/TC)

typedef __bf16 bft;
typedef __bf16 bf16x8 __attribute__((ext_vector_type(8)));
typedef float f32x4 __attribute__((ext_vector_type(4)));

// async global->LDS, 16B per lane. lds base must be wave-uniform; lane i's data
// lands at base + i*16, so lane i's global ptr must be the data for that slot.
__device__ __forceinline__ void gl_lds16(const bft* g, void* lds_base_uniform) {
  __builtin_amdgcn_global_load_lds(
      (const __attribute__((address_space(1))) void*)g,
      (__attribute__((address_space(3))) void*)lds_base_uniform,
      16, 0, 0);
}

// ---------------- fp32 -> bf16 convert (vectorized 8/thread) ----------------
__global__ void k_cvt(const float* __restrict__ in, bft* __restrict__ out, long n) {
  long i = ((long)blockIdx.x * blockDim.x + threadIdx.x) * 8;
  long stride = (long)gridDim.x * blockDim.x * 8;
  for (; i < n; i += stride) {
    float4 a = *(const float4*)(in + i);
    float4 b = *(const float4*)(in + i + 4);
    bf16x8 r;
    r[0] = (bft)a.x; r[1] = (bft)a.y; r[2] = (bft)a.z; r[3] = (bft)a.w;
    r[4] = (bft)b.x; r[5] = (bft)b.y; r[6] = (bft)b.z; r[7] = (bft)b.w;
    *(bf16x8*)(out + i) = r;
  }
}

// ---------------- generic bf16 GEMM: C[m,n] = sum_k A[m,k]*W[n,k] + bias[n] --
// BM=BN=128, BK=64, 256 threads (4 waves as 2x2, each wave 64x64 = 4x4 frags).
// CHUNKED: A row m maps to global row (m>>5)*TT + t0 + (m&31)  (b,t packing).
// EPI==0: store bf16 (x_proj). EPI==1: store fp32 silu(v) (logits).
template<bool CHUNKED, int EPI>
__launch_bounds__(256)
__global__ void k_gemm(const bft* __restrict__ A, long lda,
                       const bft* __restrict__ W, long ldw,
                       const float* __restrict__ bias,
                       void* __restrict__ Cout, long ldc,
                       int t0, int K) {
  __shared__ unsigned char sm[32768];   // A tile 16KB | W tile 16KB
  const int tid  = threadIdx.x;
  const int lane = tid & 63;
  const int wid  = tid >> 6;
  const int m0 = blockIdx.y * 128;
  const int n0 = blockIdx.x * 128;
  const int wm = wid >> 1, wn = wid & 1;

  f32x4 acc[4][4] = {};

  for (int k0 = 0; k0 < K; k0 += 64) {
    // stage A tile: LDS [128][64] bf16, rows 128B; XOR-swizzle byte^=((row&7)<<4)
    // applied on the SOURCE so LDS stays linear (global_load_lds constraint).
#pragma unroll
    for (int s = 0; s < 4; ++s) {
      int seg = wid * 4 + s;
      int row = seg * 8 + (lane >> 3);
      int cbs = ((lane & 7) * 16) ^ ((row & 7) << 4);
      long grow = CHUNKED ? ((long)(row + m0 >> 5) * TT + t0 + ((row + m0) & 31))
                          : (long)(m0 + row);
      gl_lds16(A + grow * lda + k0 + (cbs >> 1), sm + seg * 1024);
    }
    // stage W tile at +16384
#pragma unroll
    for (int s = 0; s < 4; ++s) {
      int seg = wid * 4 + s;
      int row = seg * 8 + (lane >> 3);
      int cbs = ((lane & 7) * 16) ^ ((row & 7) << 4);
      gl_lds16(W + (long)(n0 + row) * ldw + k0 + (cbs >> 1), sm + 16384 + seg * 1024);
    }
    __syncthreads();
#pragma unroll
    for (int ks = 0; ks < 2; ++ks) {
      int kb = ks * 64 + (lane >> 4) * 16;  // byte offset of this lane's 8 k's
      bf16x8 aF[4], bF[4];
#pragma unroll
      for (int mi = 0; mi < 4; ++mi) {
        int row = wm * 64 + mi * 16 + (lane & 15);
        aF[mi] = *(const bf16x8*)(sm + row * 128 + (kb ^ ((row & 7) << 4)));
      }
#pragma unroll
      for (int ni = 0; ni < 4; ++ni) {
        int row = wn * 64 + ni * 16 + (lane & 15);
        bF[ni] = *(const bf16x8*)(sm + 16384 + row * 128 + (kb ^ ((row & 7) << 4)));
      }
#pragma unroll
      for (int mi = 0; mi < 4; ++mi)
#pragma unroll
        for (int ni = 0; ni < 4; ++ni)
          acc[mi][ni] = __builtin_amdgcn_mfma_f32_16x16x32_bf16(aF[mi], bF[ni], acc[mi][ni], 0, 0, 0);
    }
    __syncthreads();
  }

  // epilogue: D layout col=lane&15, row=(lane>>4)*4+reg
#pragma unroll
  for (int mi = 0; mi < 4; ++mi)
#pragma unroll
    for (int ni = 0; ni < 4; ++ni) {
      int col = n0 + wn * 64 + ni * 16 + (lane & 15);
      float bv = bias[col];
#pragma unroll
      for (int r = 0; r < 4; ++r) {
        long row = m0 + wm * 64 + mi * 16 + (lane >> 4) * 4 + r;
        float v = acc[mi][ni][r] + bv;
        if (EPI == 0) {
          ((bft*)Cout)[row * ldc + col] = (bft)v;
        } else {
          ((float*)Cout)[row * ldc + col] = v / (1.f + expf(-v));
        }
      }
    }
}

// ---------------- fused GRU step ----------------
// Computes hp = h @ Whh^T (+bhh) for all 3 gates, then the GRU cell.
// Grid (32,8): x = 32-col tile per gate, y = 64-batch-row tile. 256 thr = 4 waves 2x2.
__launch_bounds__(256)
__global__ void k_step(const bft* __restrict__ hb_in, long his,
                       const bft* __restrict__ whh,
                       const float* __restrict__ bhh,
                       const bft* __restrict__ xp, int tc,
                       const float* __restrict__ h_in,
                       float* __restrict__ h_out,
                       bft* __restrict__ hb_out, long hos) {
  __shared__ unsigned char sm[8192 + 12288];  // A 64x64 (8KB) | B 3x(32x64) (12KB)
  const int tid  = threadIdx.x;
  const int lane = tid & 63;
  const int wid  = tid >> 6;
  const int n0 = blockIdx.x * 32;
  const int m0 = blockIdx.y * 64;
  const int wm = wid >> 1, wn = wid & 1;

  f32x4 acc[3][2] = {};

  for (int k0 = 0; k0 < 1024; k0 += 64) {
    // A: h rows [m0, m0+64), stride his (elements)
#pragma unroll
    for (int s = 0; s < 2; ++s) {
      int seg = wid * 2 + s;
      int row = seg * 8 + (lane >> 3);
      int cbs = ((lane & 7) * 16) ^ ((row & 7) << 4);
      gl_lds16(hb_in + (long)(m0 + row) * his + k0 + (cbs >> 1), sm + seg * 1024);
    }
    // B: per gate 32 rows of whh
#pragma unroll
    for (int g = 0; g < 3; ++g) {
      int row = wid * 8 + (lane >> 3);
      int cbs = ((lane & 7) * 16) ^ ((row & 7) << 4);
      gl_lds16(whh + (long)(g * 1024 + n0 + row) * 1024 + k0 + (cbs >> 1),
               sm + 8192 + g * 4096 + wid * 1024);
    }
    __syncthreads();
#pragma unroll
    for (int ks = 0; ks < 2; ++ks) {
      int kb = ks * 64 + (lane >> 4) * 16;
      bf16x8 aF[2], bF[3];
#pragma unroll
      for (int mi = 0; mi < 2; ++mi) {
        int row = wm * 32 + mi * 16 + (lane & 15);
        aF[mi] = *(const bf16x8*)(sm + row * 128 + (kb ^ ((row & 7) << 4)));
      }
#pragma unroll
      for (int g = 0; g < 3; ++g) {
        int row = wn * 16 + (lane & 15);
        bF[g] = *(const bf16x8*)(sm + 8192 + g * 4096 + row * 128 + (kb ^ ((row & 7) << 4)));
      }
#pragma unroll
      for (int g = 0; g < 3; ++g)
#pragma unroll
        for (int mi = 0; mi < 2; ++mi)
          acc[g][mi] = __builtin_amdgcn_mfma_f32_16x16x32_bf16(aF[mi], bF[g], acc[g][mi], 0, 0, 0);
    }
    __syncthreads();
  }

  // epilogue: GRU cell
  int j = n0 + wn * 16 + (lane & 15);
  float br = bhh[j], bz = bhh[1024 + j], bn = bhh[2048 + j];
#pragma unroll
  for (int mi = 0; mi < 2; ++mi) {
#pragma unroll
    for (int r = 0; r < 4; ++r) {
      long b = m0 + wm * 32 + mi * 16 + (lane >> 4) * 4 + r;
      long xrow = (b * TC + tc) * (long)G3;
      float xr = (float)xp[xrow + j];
      float xz = (float)xp[xrow + 1024 + j];
      float xn = (float)xp[xrow + 2048 + j];
      float hr = acc[0][mi][r] + br;
      float hz = acc[1][mi][r] + bz;
      float hn = acc[2][mi][r] + bn;
      float rg = 1.f / (1.f + expf(-(xr + hr)));
      float zg = 1.f / (1.f + expf(-(xz + hz)));
      float ng = tanhf(xn + rg * hn);
      float hprev = h_in[b * 1024 + j];
      float hv = (1.f - zg) * ng + zg * hprev;
      h_out[b * 1024 + j] = hv;
      hb_out[b * hos + j] = (bft)hv;
    }
  }
}

// ---------------- softmax + rebalance (one block per row) ----------------
__device__ __forceinline__ float blk_sum(float v, float* red, int tid) {
#pragma unroll
  for (int o = 32; o; o >>= 1) v += __shfl_xor(v, o);
  if ((tid & 63) == 0) red[tid >> 6] = v;
  __syncthreads();
  v = red[0] + red[1] + red[2] + red[3];
  __syncthreads();
  return v;
}
__device__ __forceinline__ float blk_max(float v, float* red, int tid) {
#pragma unroll
  for (int o = 32; o; o >>= 1) v = fmaxf(v, __shfl_xor(v, o));
  if ((tid & 63) == 0) red[tid >> 6] = v;
  __syncthreads();
  v = fmaxf(fmaxf(red[0], red[1]), fmaxf(red[2], red[3]));
  __syncthreads();
  return v;
}

__launch_bounds__(256)
__global__ void k_smrebal(const float* __restrict__ logits, float* __restrict__ out) {
  __shared__ float red[4];
  const int tid = threadIdx.x;
  const long row = blockIdx.x;
  const float ub = 0.2f, lb = 0.0f;
  float4 lv = *(const float4*)(logits + row * 1024 + tid * 4);

  float m = fmaxf(fmaxf(lv.x, lv.y), fmaxf(lv.z, lv.w));
  m = blk_max(m, red, tid);
  float e[4] = {expf(lv.x - m), expf(lv.y - m), expf(lv.z - m), expf(lv.w - m)};
  float S = blk_sum(e[0] + e[1] + e[2] + e[3], red, tid);

  float old_[4], wc[4];
#pragma unroll
  for (int k = 0; k < 4; ++k) {
    float p = e[k] / S;
    old_[k] = p;
    wc[k] = fminf(fmaxf(p, lb), ub);
  }
  bool done = false;
  for (int it = 0; it < 32 && !done; ++it) {
    float d3 = 0.f, cnt = 0.f, nsum = 0.f;
#pragma unroll
    for (int k = 0; k < 4; ++k) {
      d3 += old_[k] - wc[k];
      bool mk = (wc[k] != ub);
      cnt += mk ? 1.f : 0.f;
      nsum += mk ? wc[k] : 0.f;
    }
    float leftover = blk_sum(d3, red, tid);
    float num = blk_sum(cnt, red, tid);
    float nom_sum = blk_sum(nsum, red, tid);
    float denom = (nom_sum == 0.f) ? 1.f : nom_sum;
    float wcn[4], mx = -1e30f;
#pragma unroll
    for (int k = 0; k < 4; ++k) {
      bool mk = (wc[k] != ub);
      wcn[k] = mk ? wc[k] + leftover * wc[k] / denom : wc[k];
      mx = fmaxf(mx, wcn[k]);
    }
    float gmx = blk_max(mx, red, tid);
    bool no_nom = (num == 0.f);
    bool over = (gmx > ub);
#pragma unroll
    for (int k = 0; k < 4; ++k) {
      float nxt = no_nom ? wc[k] : (over ? fminf(fmaxf(wcn[k], lb), ub) : wcn[k]);
      float oldn = no_nom ? old_[k] : wcn[k];
      wc[k] = nxt;
      old_[k] = oldn;
    }
    done = no_nom || !over;
  }
#pragma unroll
  for (int k = 0; k < 4; ++k) out[row * 1024 + tid * 4 + k] = wc[k];
}

// ---------------- host ----------------
extern "C" void kernel_launch(void* const* d_in, const int* in_sizes, int n_in,
                              void* d_out, int out_size, void* d_ws, size_t ws_size,
                              hipStream_t stream) {
  const float* x      = (const float*)d_in[0];
  const float* wih[2] = {(const float*)d_in[1], (const float*)d_in[5]};
  const float* whh[2] = {(const float*)d_in[2], (const float*)d_in[6]};
  const float* bih[2] = {(const float*)d_in[3], (const float*)d_in[7]};
  const float* bhh[2] = {(const float*)d_in[4], (const float*)d_in[8]};
  const float* fcw    = (const float*)d_in[9];
  const float* fcb    = (const float*)d_in[10];
  float* outp = (float*)d_out;

  unsigned char* ws = (unsigned char*)d_ws;
  size_t off = 0;
  auto alloc = [&](size_t bytes) -> void* {
    void* p = ws + off;
    off += (bytes + 255) & ~(size_t)255;
    return p;
  };
  bft* xb      = (bft*)alloc((size_t)BB * TT * DD * 2);   // x bf16; becomes layer-0 h-seq
  bft* wihb0   = (bft*)alloc((size_t)G3 * DD * 2);
  bft* whhb0   = (bft*)alloc((size_t)G3 * HH * 2);
  bft* wihb1   = (bft*)alloc((size_t)G3 * HH * 2);
  bft* whhb1   = (bft*)alloc((size_t)G3 * HH * 2);
  bft* fcwb    = (bft*)alloc((size_t)1024 * 1024 * 2);
  bft* xp      = (bft*)alloc((size_t)BB * TC * G3 * 2);   // chunk x_proj
  float* hA    = (float*)alloc((size_t)BB * HH * 4);
  float* hB    = (float*)alloc((size_t)BB * HH * 4);
  bft* hbA     = (bft*)alloc((size_t)BB * HH * 2);
  bft* hbB     = (bft*)alloc((size_t)BB * HH * 2);
  float* logits= (float*)alloc((size_t)BB * 1024 * 4);
  if (off > ws_size) return;  // insufficient workspace: leave output poisoned

  bft* wihb[2] = {wihb0, wihb1};
  bft* whhb[2] = {whhb0, whhb1};

  // converts
  k_cvt<<<dim3(4096), dim3(256), 0, stream>>>(x, xb, (long)BB * TT * DD);
  k_cvt<<<dim3(1536), dim3(256), 0, stream>>>(wih[0], wihb[0], (long)G3 * DD);
  k_cvt<<<dim3(1536), dim3(256), 0, stream>>>(whh[0], whhb[0], (long)G3 * HH);
  k_cvt<<<dim3(1536), dim3(256), 0, stream>>>(wih[1], wihb[1], (long)G3 * HH);
  k_cvt<<<dim3(1536), dim3(256), 0, stream>>>(whh[1], whhb[1], (long)G3 * HH);
  k_cvt<<<dim3(512),  dim3(256), 0, stream>>>(fcw, fcwb, (long)1024 * 1024);

  for (int l = 0; l < 2; ++l) {
    hipMemsetAsync(hA, 0, (size_t)BB * HH * 4, stream);
    hipMemsetAsync(hbA, 0, (size_t)BB * HH * 2, stream);
    for (int c = 0; c < NCH; ++c) {
      int t0 = c * TC;
      // x_proj for this chunk: M = BB*TC = 16384, N = 3072, K = 1024
      k_gemm<true, 0><<<dim3(G3 / 128, (BB * TC) / 128), 256, 0, stream>>>(
          xb, DD, wihb[l], DD, bih[l], xp, G3, t0, DD);
      for (int tcx = 0; tcx < TC; ++tcx) {
        int t = t0 + tcx;
        const bft* hbi; long his;
        if (t == 0)      { hbi = hbA; his = HH; }
        else if (l == 0) { hbi = xb + (long)(t - 1) * DD; his = (long)TT * DD; }
        else             { hbi = (t & 1) ? hbB : hbA; his = HH; }
        bft* hbo; long hos;
        if (l == 0) { hbo = xb + (long)t * DD; hos = (long)TT * DD; }
        else        { hbo = (t & 1) ? hbA : hbB; hos = HH; }
        const float* hi = (t & 1) ? hB : hA;
        float* ho       = (t & 1) ? hA : hB;
        k_step<<<dim3(HH / 32, BB / 64), 256, 0, stream>>>(
            hbi, his, whhb[l], bhh[l], xp, tcx, hi, ho, hbo, hos);
      }
    }
  }
  // FC + SiLU: final h (bf16) is hbA (t=127 odd -> out=hbA)
  k_gemm<false, 1><<<dim3(1024 / 128, BB / 128), 256, 0, stream>>>(
      hbA, HH, fcwb, HH, fcb, logits, 1024, 0, HH);
  k_smrebal<<<dim3(BB), 256, 0, stream>>>(logits, outp);
}